// Round 5
// baseline (1253.303 us; speedup 1.0000x reference)
//
#include <hip/hip_runtime.h>

#define NWIN 49
#define CDIM 128
#define SCALEQ 0.17677669529663687f

typedef _Float16 half8 __attribute__((ext_vector_type(8)));
typedef _Float16 half4v __attribute__((ext_vector_type(4)));
typedef float f32x4 __attribute__((ext_vector_type(4)));

// strides in halves (f16 elements)
#define XL_STR 136   // x / O tile row stride (272 B)
#define QK_STR 40    // Q,K row stride (80 B)
#define P_STR  72    // P row stride (144 B)
#define VT_STR 72    // V^T row stride (144 B; 64 token cols + pad)

#define XBUF_H   (NWIN * XL_STR)              // 6664 halves per x buffer
#define PRIV0_H  (2 * XBUF_H)                 // 13328
#define K_OFF_H  (NWIN * QK_STR)              // 1960: K after Q
#define VT_OFF_H (2 * K_OFF_H)                // 3920: VT after Q|K (P overlays Q|K: 3528 <= 3920)
#define PRIV_H   (VT_OFF_H + 32 * VT_STR)     // 6224 halves per HEAD
#define SMEM_H   (PRIV0_H + 4 * PRIV_H)       // 38224 halves = 76448 B

// 512 threads = 8 waves: wave w = (head h = w>>1, col-half c = w&1).
// LDS total 76448 + 2048 (sums) = 78496 B -> 2 blocks/CU, 4 waves/EU.
__global__ __launch_bounds__(512, 4)
void lwa_fused(const float* x,
               const float* w_qkv,
               const float* b_qkv,
               const float* w_proj,
               const float* b_proj,
               const float* bias_table,
               const int* rel_index,
               float* out,
               int nwin_total, int wpb)
{
    __shared__ __align__(16) _Float16 smem[SMEM_H];
    __shared__ float sums[4 * 2 * 64];   // [head][c][64 q-slots]

    const int tid  = threadIdx.x;
    const int w    = tid >> 6;       // 0..7
    const int h    = w >> 1;         // head 0..3
    const int c    = w & 1;          // 16-col half within head
    const int lane = tid & 63;
    const int lo   = lane & 15;
    const int hi   = lane >> 4;
    const int ncol = 32 * h + 16 * c + lo;   // this lane's output column (head-dim space)

    _Float16* const Qh  = smem + PRIV0_H + h * PRIV_H;   // 49 x 32, stride 40 (per head)
    _Float16* const Kh  = Qh + K_OFF_H;                  // 49 x 32, stride 40
    _Float16* const Ph  = Qh;                            // overlay: 49 x 64, stride 72
    _Float16* const VTh = Qh + VT_OFF_H;                 // 32 x 64, stride 72

    // ---------- per-block setup (registers) ----------
    // wb1[tn][kk]: B-frag of w_qkv for tn in {q,k,v}, this wave's 16 cols. 48 VGPRs.
    half8 wb1[3][4];
    float bq[3];
#pragma unroll
    for (int tn = 0; tn < 3; ++tn) {
        int n = tn * CDIM + ncol;
        float sc = (tn == 0) ? SCALEQ : 1.0f;
        bq[tn] = b_qkv[n] * sc;
#pragma unroll
        for (int kk = 0; kk < 4; ++kk) {
            const float* p = w_qkv + (size_t)n * CDIM + kk * 32 + hi * 8;
            float4 u0 = *reinterpret_cast<const float4*>(p);
            float4 u1 = *reinterpret_cast<const float4*>(p + 4);
            half8 hh;
            hh[0] = (_Float16)(u0.x * sc); hh[1] = (_Float16)(u0.y * sc);
            hh[2] = (_Float16)(u0.z * sc); hh[3] = (_Float16)(u0.w * sc);
            hh[4] = (_Float16)(u1.x * sc); hh[5] = (_Float16)(u1.y * sc);
            hh[6] = (_Float16)(u1.z * sc); hh[7] = (_Float16)(u1.w * sc);
            wb1[tn][kk] = hh;
        }
    }
    const float bp = b_proj[ncol];

    // biasp[kt][tnq]: this wave's key-range only (keys 16*(2c+kt)+4hi+j). 16 VGPRs.
    half4v biasp[2][4];
#pragma unroll
    for (int kt = 0; kt < 2; ++kt)
#pragma unroll
        for (int tnq = 0; tnq < 4; ++tnq) {
            int q = 16 * tnq + lo;
            int qc = (q < 49) ? q : 48;
            half4v hv;
#pragma unroll
            for (int j = 0; j < 4; ++j) {
                int key = 16 * (2 * c + kt) + 4 * hi + j;
                float bv = (key >= 49) ? -1e4f
                         : bias_table[(size_t)rel_index[qc * 49 + key] * 4 + h];
                hv[j] = (_Float16)bv;
            }
            biasp[kt][tnq] = hv;
        }

    const f32x4 zf = {0.f, 0.f, 0.f, 0.f};

    int b0 = blockIdx.x * wpb;
    int b1 = b0 + wpb; if (b1 > nwin_total) b1 = nwin_total;

    // ---------- staging helper: x[bw] (f32) -> dst (f16, stride XL_STR) ----------
    auto stage = [&](int bw, _Float16* dst) {
        const float* xs = x + (size_t)bw * NWIN * CDIM;
        int r0 = tid >> 4;
        int gc = (tid & 15) * 8;
#pragma unroll
        for (int p = 0; p < 2; ++p) {
            int row = r0 + p * 32;
            if (row < 49) {
                const float* sp = xs + (size_t)row * CDIM + gc;
                float4 u0 = *reinterpret_cast<const float4*>(sp);
                float4 u1 = *reinterpret_cast<const float4*>(sp + 4);
                half8 hh;
                hh[0] = (_Float16)u0.x; hh[1] = (_Float16)u0.y;
                hh[2] = (_Float16)u0.z; hh[3] = (_Float16)u0.w;
                hh[4] = (_Float16)u1.x; hh[5] = (_Float16)u1.y;
                hh[6] = (_Float16)u1.z; hh[7] = (_Float16)u1.w;
                *reinterpret_cast<half8*>(&dst[row * XL_STR + gc]) = hh;
            }
        }
    };

    stage(b0, smem);
    __syncthreads();

    // ---------- window loop ----------
    for (int b = b0; b < b1; ++b) {
        const int par = (b - b0) & 1;
        _Float16* const xb = smem + (par ? XBUF_H : 0);   // current x; later O
        _Float16* const xn = smem + (par ? 0 : XBUF_H);   // next x

        // wb3 streamed per window (may-alias with out stores -> not hoisted).
        // Loads issue here; latency hides under staging + GEMM1.
        half8 wb3h[4];
#pragma unroll
        for (int kk = 0; kk < 4; ++kk) {
            const float* p = w_proj + (size_t)ncol * CDIM + kk * 32 + hi * 8;
            float4 u0 = *reinterpret_cast<const float4*>(p);
            float4 u1 = *reinterpret_cast<const float4*>(p + 4);
            half8 hh;
            hh[0] = (_Float16)u0.x; hh[1] = (_Float16)u0.y;
            hh[2] = (_Float16)u0.z; hh[3] = (_Float16)u0.w;
            hh[4] = (_Float16)u1.x; hh[5] = (_Float16)u1.y;
            hh[6] = (_Float16)u1.z; hh[7] = (_Float16)u1.w;
            wb3h[kk] = hh;
        }

        if (b + 1 < b1) stage(b + 1, xn);

        // ---- GEMM1: this wave's 16 cols of q,k,v ----
#pragma unroll
        for (int tm = 0; tm < 4; ++tm) {
            int ar = 16 * tm + lo; if (ar > 48) ar = 48;
            half8 a[4];
#pragma unroll
            for (int kk = 0; kk < 4; ++kk)
                a[kk] = *reinterpret_cast<const half8*>(&xb[ar * XL_STR + kk * 32 + hi * 8]);
            f32x4 acc[3];
#pragma unroll
            for (int tn = 0; tn < 3; ++tn) {
                acc[tn][0] = bq[tn]; acc[tn][1] = bq[tn];
                acc[tn][2] = bq[tn]; acc[tn][3] = bq[tn];
            }
#pragma unroll
            for (int tn = 0; tn < 3; ++tn)
#pragma unroll
                for (int kk = 0; kk < 4; ++kk)
                    acc[tn] = __builtin_amdgcn_mfma_f32_16x16x32_f16(a[kk], wb1[tn][kk], acc[tn], 0, 0, 0);
            // epilogue: Q,K scalar f16 (rows), V transposed packed
#pragma unroll
            for (int j = 0; j < 4; ++j) {
                int row = 16 * tm + 4 * hi + j;
                if (row < 49) {
                    Qh[row * QK_STR + 16 * c + lo] = (_Float16)acc[0][j];
                    Kh[row * QK_STR + 16 * c + lo] = (_Float16)acc[1][j];
                }
            }
            half4v hv;
#pragma unroll
            for (int j = 0; j < 4; ++j) hv[j] = (_Float16)acc[2][j];
            *reinterpret_cast<half4v*>(&VTh[(16 * c + lo) * VT_STR + 16 * tm + 4 * hi]) = hv;
        }
        __syncthreads();  // B1: Q,K,VT visible; xb reads done

        // ---- hoist all K,Q fragment reads (P overlays Q|K) ----
        half8 kf[2], qf[4];
#pragma unroll
        for (int kt = 0; kt < 2; ++kt) {
            int kr = 16 * (2 * c + kt) + lo; if (kr > 48) kr = 48;
            kf[kt] = *reinterpret_cast<const half8*>(&Kh[kr * QK_STR + hi * 8]);
        }
#pragma unroll
        for (int t = 0; t < 4; ++t)
            qf[t] = *reinterpret_cast<const half8*>(&Qh[(16 * t + lo) * QK_STR + hi * 8]);
        __syncthreads();  // B2: all Q/K reads done -> P region writable

        // ---- S^T slice (this wave's 32 keys), exp, P stores, partial sums ----
#pragma unroll
        for (int tnq = 0; tnq < 4; ++tnq) {
            float sum = 0.f;
            int q = 16 * tnq + lo;
#pragma unroll
            for (int kt = 0; kt < 2; ++kt) {
                f32x4 s = __builtin_amdgcn_mfma_f32_16x16x32_f16(kf[kt], qf[tnq], zf, 0, 0, 0);
                half4v hv;
#pragma unroll
                for (int j = 0; j < 4; ++j) {
                    float pv = __expf(s[j] + (float)biasp[kt][tnq][j]);
                    sum += pv;
                    hv[j] = (_Float16)pv;
                }
                if (q < 49)
                    *reinterpret_cast<half4v*>(&Ph[q * P_STR + 16 * (2 * c + kt) + 4 * hi]) = hv;
            }
            sum += __shfl_xor(sum, 16);
            sum += __shfl_xor(sum, 32);
            if (hi == 0) sums[h * 128 + c * 64 + q] = sum;
        }
        __syncthreads();  // B3: P + partial sums visible

        // ---- PV: O^T slice (this wave's 16 d-dims), normalized O -> xb ----
        {
            half8 vf[2];
#pragma unroll
            for (int kk = 0; kk < 2; ++kk)
                vf[kk] = *reinterpret_cast<const half8*>(&VTh[(16 * c + lo) * VT_STR + kk * 32 + hi * 8]);
#pragma unroll
            for (int tnq = 0; tnq < 4; ++tnq) {
                int q = 16 * tnq + lo;
                f32x4 o = zf;
#pragma unroll
                for (int kk = 0; kk < 2; ++kk) {
                    half8 pf = *reinterpret_cast<const half8*>(&Ph[q * P_STR + kk * 32 + hi * 8]);
                    o = __builtin_amdgcn_mfma_f32_16x16x32_f16(vf[kk], pf, o, 0, 0, 0);
                }
                if (q < 49) {
                    float invl = 1.0f / (sums[h * 128 + q] + sums[h * 128 + 64 + q]);
                    half4v hv;
#pragma unroll
                    for (int j = 0; j < 4; ++j) hv[j] = (_Float16)(o[j] * invl);
                    *reinterpret_cast<half4v*>(&xb[q * XL_STR + 32 * h + 16 * c + 4 * hi]) = hv;
                }
            }
        }
        __syncthreads();  // B4: O complete

        // ---- GEMM3: out = O @ w_proj^T + b_proj (this wave's 16 cols) ----
#pragma unroll
        for (int tm = 0; tm < 4; ++tm) {
            int orr = 16 * tm + lo; if (orr > 48) orr = 48;
            f32x4 g; g[0] = bp; g[1] = bp; g[2] = bp; g[3] = bp;
#pragma unroll
            for (int kk = 0; kk < 4; ++kk) {
                half8 oa = *reinterpret_cast<const half8*>(&xb[orr * XL_STR + kk * 32 + hi * 8]);
                g = __builtin_amdgcn_mfma_f32_16x16x32_f16(oa, wb3h[kk], g, 0, 0, 0);
            }
#pragma unroll
            for (int j = 0; j < 4; ++j) {
                int row = 16 * tm + 4 * hi + j;
                if (row < 49)
                    out[((size_t)b * NWIN + row) * CDIM + ncol] = g[j];
            }
        }
        __syncthreads();  // B5: xb (O) reads done -> next iter may stage into it
    }
}

extern "C" void kernel_launch(void* const* d_in, const int* in_sizes, int n_in,
                              void* d_out, int out_size, void* d_ws, size_t ws_size,
                              hipStream_t stream) {
    const float* x          = (const float*)d_in[0];
    // d_in[1] = q_global: unused by the reference
    const float* w_qkv      = (const float*)d_in[2];
    const float* b_qkv      = (const float*)d_in[3];
    const float* w_proj     = (const float*)d_in[4];
    const float* b_proj     = (const float*)d_in[5];
    const float* bias_table = (const float*)d_in[6];
    const int*   rel_index  = (const int*)d_in[7];

    const int nwin = in_sizes[0] / (NWIN * CDIM);   // 16384
    const int wpb = 16;
    const int nblk = (nwin + wpb - 1) / wpb;        // 1024

    lwa_fused<<<nblk, 512, 0, stream>>>(x, w_qkv, b_qkv, w_proj, b_proj,
                                        bias_table, rel_index, (float*)d_out,
                                        nwin, wpb);
}

// Round 6
// 772.670 us; speedup vs baseline: 1.6220x; 1.6220x over previous
//
#include <hip/hip_runtime.h>

#define NWIN 49
#define CDIM 128
#define SCALEQ 0.17677669529663687f

typedef _Float16 half8 __attribute__((ext_vector_type(8)));
typedef _Float16 half4v __attribute__((ext_vector_type(4)));
typedef float f32x4 __attribute__((ext_vector_type(4)));

// strides in halves (f16 elements)
#define XL_STR 136   // x / O tile row stride (272 B)
#define QK_STR 40    // Q,K row stride (80 B)
#define P_STR  72    // P row stride (144 B)
#define VT_STR 72    // V^T row stride (144 B; 64 token cols + pad)

#define XBUF_H   (NWIN * XL_STR)              // 6664 halves per x buffer
#define PRIV0_H  (2 * XBUF_H)                 // 13328
#define K_OFF_H  (NWIN * QK_STR)              // 1960: K after Q
#define VT_OFF_H (2 * K_OFF_H)                // 3920: VT after Q|K (P overlays Q|K: 3528 <= 3920)
#define PRIV_H   (VT_OFF_H + 32 * VT_STR)     // 6224 halves per HEAD
#define SMEM_H   (PRIV0_H + 4 * PRIV_H)       // 38224 halves = 76448 B

// 512 threads = 8 waves: wave w = (head h = w>>1, col-half c = w&1).
// LDS total 76448 + 2048 (sums) = 78496 B -> 2 blocks/CU = 16 waves/CU = 4 waves/EU.
// Occupancy is LDS-bound at 4 waves/EU; pin the allocator to exactly that so it
// budgets 128 VGPRs instead of chasing 8 waves/EU with a 64-reg budget (round-5
// failure: VGPR=64, 2.4 GB scratch FETCH). Attribute-only: no __launch_bounds__.
__global__ __attribute__((amdgpu_flat_work_group_size(512, 512), amdgpu_waves_per_eu(4, 4)))
void lwa_fused(const float* x,
               const float* w_qkv,
               const float* b_qkv,
               const float* w_proj,
               const float* b_proj,
               const float* bias_table,
               const int* rel_index,
               float* out,
               int nwin_total, int wpb)
{
    __shared__ __align__(16) _Float16 smem[SMEM_H];
    __shared__ float sums[4 * 2 * 64];   // [head][c][64 q-slots]

    const int tid  = threadIdx.x;
    const int w    = tid >> 6;       // 0..7
    const int h    = w >> 1;         // head 0..3
    const int c    = w & 1;          // 16-col half within head
    const int lane = tid & 63;
    const int lo   = lane & 15;
    const int hi   = lane >> 4;
    const int ncol = 32 * h + 16 * c + lo;   // this lane's output column (head-dim space)

    _Float16* const Qh  = smem + PRIV0_H + h * PRIV_H;   // 49 x 32, stride 40 (per head)
    _Float16* const Kh  = Qh + K_OFF_H;                  // 49 x 32, stride 40
    _Float16* const Ph  = Qh;                            // overlay: 49 x 64, stride 72
    _Float16* const VTh = Qh + VT_OFF_H;                 // 32 x 64, stride 72

    // ---------- per-block setup (registers) ----------
    // wb1[tn][kk]: B-frag of w_qkv for tn in {q,k,v}, this wave's 16 cols. 48 VGPRs.
    half8 wb1[3][4];
    float bq[3];
#pragma unroll
    for (int tn = 0; tn < 3; ++tn) {
        int n = tn * CDIM + ncol;
        float sc = (tn == 0) ? SCALEQ : 1.0f;
        bq[tn] = b_qkv[n] * sc;
#pragma unroll
        for (int kk = 0; kk < 4; ++kk) {
            const float* p = w_qkv + (size_t)n * CDIM + kk * 32 + hi * 8;
            float4 u0 = *reinterpret_cast<const float4*>(p);
            float4 u1 = *reinterpret_cast<const float4*>(p + 4);
            half8 hh;
            hh[0] = (_Float16)(u0.x * sc); hh[1] = (_Float16)(u0.y * sc);
            hh[2] = (_Float16)(u0.z * sc); hh[3] = (_Float16)(u0.w * sc);
            hh[4] = (_Float16)(u1.x * sc); hh[5] = (_Float16)(u1.y * sc);
            hh[6] = (_Float16)(u1.z * sc); hh[7] = (_Float16)(u1.w * sc);
            wb1[tn][kk] = hh;
        }
    }
    const float bp = b_proj[ncol];

    // biasp[kt][tnq]: this wave's key-range only (keys 16*(2c+kt)+4hi+j). 16 VGPRs.
    half4v biasp[2][4];
#pragma unroll
    for (int kt = 0; kt < 2; ++kt)
#pragma unroll
        for (int tnq = 0; tnq < 4; ++tnq) {
            int q = 16 * tnq + lo;
            int qc = (q < 49) ? q : 48;
            half4v hv;
#pragma unroll
            for (int j = 0; j < 4; ++j) {
                int key = 16 * (2 * c + kt) + 4 * hi + j;
                float bv = (key >= 49) ? -1e4f
                         : bias_table[(size_t)rel_index[qc * 49 + key] * 4 + h];
                hv[j] = (_Float16)bv;
            }
            biasp[kt][tnq] = hv;
        }

    const f32x4 zf = {0.f, 0.f, 0.f, 0.f};

    int b0 = blockIdx.x * wpb;
    int b1 = b0 + wpb; if (b1 > nwin_total) b1 = nwin_total;

    // ---------- staging helper: x[bw] (f32) -> dst (f16, stride XL_STR) ----------
    auto stage = [&](int bw, _Float16* dst) {
        const float* xs = x + (size_t)bw * NWIN * CDIM;
        int r0 = tid >> 4;
        int gc = (tid & 15) * 8;
#pragma unroll
        for (int p = 0; p < 2; ++p) {
            int row = r0 + p * 32;
            if (row < 49) {
                const float* sp = xs + (size_t)row * CDIM + gc;
                float4 u0 = *reinterpret_cast<const float4*>(sp);
                float4 u1 = *reinterpret_cast<const float4*>(sp + 4);
                half8 hh;
                hh[0] = (_Float16)u0.x; hh[1] = (_Float16)u0.y;
                hh[2] = (_Float16)u0.z; hh[3] = (_Float16)u0.w;
                hh[4] = (_Float16)u1.x; hh[5] = (_Float16)u1.y;
                hh[6] = (_Float16)u1.z; hh[7] = (_Float16)u1.w;
                *reinterpret_cast<half8*>(&dst[row * XL_STR + gc]) = hh;
            }
        }
    };

    stage(b0, smem);
    __syncthreads();

    // ---------- window loop ----------
    for (int b = b0; b < b1; ++b) {
        const int par = (b - b0) & 1;
        _Float16* const xb = smem + (par ? XBUF_H : 0);   // current x; later O
        _Float16* const xn = smem + (par ? 0 : XBUF_H);   // next x

        if (b + 1 < b1) stage(b + 1, xn);

        // ---- GEMM1: this wave's 16 cols of q,k,v ----
#pragma unroll
        for (int tm = 0; tm < 4; ++tm) {
            int ar = 16 * tm + lo; if (ar > 48) ar = 48;
            half8 a[4];
#pragma unroll
            for (int kk = 0; kk < 4; ++kk)
                a[kk] = *reinterpret_cast<const half8*>(&xb[ar * XL_STR + kk * 32 + hi * 8]);
            f32x4 acc[3];
#pragma unroll
            for (int tn = 0; tn < 3; ++tn) {
                acc[tn][0] = bq[tn]; acc[tn][1] = bq[tn];
                acc[tn][2] = bq[tn]; acc[tn][3] = bq[tn];
            }
#pragma unroll
            for (int tn = 0; tn < 3; ++tn)
#pragma unroll
                for (int kk = 0; kk < 4; ++kk)
                    acc[tn] = __builtin_amdgcn_mfma_f32_16x16x32_f16(a[kk], wb1[tn][kk], acc[tn], 0, 0, 0);
            // epilogue: Q,K scalar f16 (rows), V transposed packed
#pragma unroll
            for (int j = 0; j < 4; ++j) {
                int row = 16 * tm + 4 * hi + j;
                if (row < 49) {
                    Qh[row * QK_STR + 16 * c + lo] = (_Float16)acc[0][j];
                    Kh[row * QK_STR + 16 * c + lo] = (_Float16)acc[1][j];
                }
            }
            half4v hv;
#pragma unroll
            for (int j = 0; j < 4; ++j) hv[j] = (_Float16)acc[2][j];
            *reinterpret_cast<half4v*>(&VTh[(16 * c + lo) * VT_STR + 16 * tm + 4 * hi]) = hv;
        }
        __syncthreads();  // B1: Q,K,VT visible; xb reads done

        // ---- hoist all K,Q fragment reads (P overlays Q|K) ----
        half8 kf[2], qf[4];
#pragma unroll
        for (int kt = 0; kt < 2; ++kt) {
            int kr = 16 * (2 * c + kt) + lo; if (kr > 48) kr = 48;
            kf[kt] = *reinterpret_cast<const half8*>(&Kh[kr * QK_STR + hi * 8]);
        }
#pragma unroll
        for (int t = 0; t < 4; ++t)
            qf[t] = *reinterpret_cast<const half8*>(&Qh[(16 * t + lo) * QK_STR + hi * 8]);
        __syncthreads();  // B2: all Q/K reads done -> P region writable

        // ---- S^T slice (this wave's 32 keys), exp, P stores, partial sums ----
#pragma unroll
        for (int tnq = 0; tnq < 4; ++tnq) {
            float sum = 0.f;
            int q = 16 * tnq + lo;
#pragma unroll
            for (int kt = 0; kt < 2; ++kt) {
                f32x4 s = __builtin_amdgcn_mfma_f32_16x16x32_f16(kf[kt], qf[tnq], zf, 0, 0, 0);
                half4v hv;
#pragma unroll
                for (int j = 0; j < 4; ++j) {
                    float pv = __expf(s[j] + (float)biasp[kt][tnq][j]);
                    sum += pv;
                    hv[j] = (_Float16)pv;
                }
                if (q < 49)
                    *reinterpret_cast<half4v*>(&Ph[q * P_STR + 16 * (2 * c + kt) + 4 * hi]) = hv;
            }
            sum += __shfl_xor(sum, 16);
            sum += __shfl_xor(sum, 32);
            if (hi == 0) sums[h * 128 + c * 64 + q] = sum;
        }

        // wb3 streamed per window, loaded HERE so its live range is only PV+GEMM3
        // and its L2 latency hides under the B3 barrier wait + PV LDS reads.
        half8 wb3h[4];
#pragma unroll
        for (int kk = 0; kk < 4; ++kk) {
            const float* p = w_proj + (size_t)ncol * CDIM + kk * 32 + hi * 8;
            float4 u0 = *reinterpret_cast<const float4*>(p);
            float4 u1 = *reinterpret_cast<const float4*>(p + 4);
            half8 hh;
            hh[0] = (_Float16)u0.x; hh[1] = (_Float16)u0.y;
            hh[2] = (_Float16)u0.z; hh[3] = (_Float16)u0.w;
            hh[4] = (_Float16)u1.x; hh[5] = (_Float16)u1.y;
            hh[6] = (_Float16)u1.z; hh[7] = (_Float16)u1.w;
            wb3h[kk] = hh;
        }
        __syncthreads();  // B3: P + partial sums visible

        // ---- PV: O^T slice (this wave's 16 d-dims), normalized O -> xb ----
        {
            half8 vf[2];
#pragma unroll
            for (int kk = 0; kk < 2; ++kk)
                vf[kk] = *reinterpret_cast<const half8*>(&VTh[(16 * c + lo) * VT_STR + kk * 32 + hi * 8]);
#pragma unroll
            for (int tnq = 0; tnq < 4; ++tnq) {
                int q = 16 * tnq + lo;
                f32x4 o = zf;
#pragma unroll
                for (int kk = 0; kk < 2; ++kk) {
                    half8 pf = *reinterpret_cast<const half8*>(&Ph[q * P_STR + kk * 32 + hi * 8]);
                    o = __builtin_amdgcn_mfma_f32_16x16x32_f16(vf[kk], pf, o, 0, 0, 0);
                }
                if (q < 49) {
                    float invl = 1.0f / (sums[h * 128 + q] + sums[h * 128 + 64 + q]);
                    half4v hv;
#pragma unroll
                    for (int j = 0; j < 4; ++j) hv[j] = (_Float16)(o[j] * invl);
                    *reinterpret_cast<half4v*>(&xb[q * XL_STR + 32 * h + 16 * c + 4 * hi]) = hv;
                }
            }
        }
        __syncthreads();  // B4: O complete

        // ---- GEMM3: out = O @ w_proj^T + b_proj (this wave's 16 cols) ----
#pragma unroll
        for (int tm = 0; tm < 4; ++tm) {
            int orr = 16 * tm + lo; if (orr > 48) orr = 48;
            f32x4 g; g[0] = bp; g[1] = bp; g[2] = bp; g[3] = bp;
#pragma unroll
            for (int kk = 0; kk < 4; ++kk) {
                half8 oa = *reinterpret_cast<const half8*>(&xb[orr * XL_STR + kk * 32 + hi * 8]);
                g = __builtin_amdgcn_mfma_f32_16x16x32_f16(oa, wb3h[kk], g, 0, 0, 0);
            }
#pragma unroll
            for (int j = 0; j < 4; ++j) {
                int row = 16 * tm + 4 * hi + j;
                if (row < 49)
                    out[((size_t)b * NWIN + row) * CDIM + ncol] = g[j];
            }
        }
        __syncthreads();  // B5: xb (O) reads done -> next iter may stage into it
    }
}

extern "C" void kernel_launch(void* const* d_in, const int* in_sizes, int n_in,
                              void* d_out, int out_size, void* d_ws, size_t ws_size,
                              hipStream_t stream) {
    const float* x          = (const float*)d_in[0];
    // d_in[1] = q_global: unused by the reference
    const float* w_qkv      = (const float*)d_in[2];
    const float* b_qkv      = (const float*)d_in[3];
    const float* w_proj     = (const float*)d_in[4];
    const float* b_proj     = (const float*)d_in[5];
    const float* bias_table = (const float*)d_in[6];
    const int*   rel_index  = (const int*)d_in[7];

    const int nwin = in_sizes[0] / (NWIN * CDIM);   // 16384
    const int wpb = 16;
    const int nblk = (nwin + wpb - 1) / wpb;        // 1024

    lwa_fused<<<nblk, 512, 0, stream>>>(x, w_qkv, b_qkv, w_proj, b_proj,
                                        bias_table, rel_index, (float*)d_out,
                                        nwin, wpb);
}

// Round 7
// 511.625 us; speedup vs baseline: 2.4497x; 1.5102x over previous
//
#include <hip/hip_runtime.h>

#define NWIN 49
#define CDIM 128
#define SCALEQ 0.17677669529663687f

typedef _Float16 half8 __attribute__((ext_vector_type(8)));
typedef _Float16 half4v __attribute__((ext_vector_type(4)));
typedef float f32x4 __attribute__((ext_vector_type(4)));

// ---- d_ws f16 layout (element offsets) ----
#define WS_WQKV  0        // [384][128] f16, q-rows (n<128) pre-scaled by SCALEQ
#define WS_WPROJ 49152    // [128][128] f16
#define WS_BQKV  65536    // [384] f16 (q part pre-scaled)
#define WS_BIAS  65920    // [4][49][64] f16: bias[h][q][key], key>=49 -> -1e4
#define WS_TOTAL 78464    // halves = 156928 B

// ---- LDS strides (halves) ----
#define XL_STR 136
#define QK_STR 40
#define P_STR  72
#define VT_STR 72

#define XBUF_H   (NWIN * XL_STR)
#define PRIV0_H  (2 * XBUF_H)
#define K_OFF_H  (NWIN * QK_STR)
#define VT_OFF_H (2 * K_OFF_H)
#define PRIV_H   (VT_OFF_H + 32 * VT_STR)
#define SMEM_H   (PRIV0_H + 4 * PRIV_H)   // 38224 halves = 76448 B

__global__ __launch_bounds__(256)
void prepack(const float* __restrict__ w_qkv, const float* __restrict__ b_qkv,
             const float* __restrict__ w_proj, const float* __restrict__ bias_table,
             const int* __restrict__ rel_index, _Float16* __restrict__ ws)
{
    int i = blockIdx.x * 256 + threadIdx.x;
    if (i < 49152) {
        float v = w_qkv[i];
        if (i < 16384) v *= SCALEQ;          // q rows (n<128)
        ws[WS_WQKV + i] = (_Float16)v;
    } else if (i < 65536) {
        ws[i] = (_Float16)w_proj[i - 49152];
    } else if (i < 65920) {
        int n = i - 65536;
        float v = b_qkv[n];
        if (n < 128) v *= SCALEQ;
        ws[WS_BQKV + n] = (_Float16)v;
    } else if (i < WS_TOTAL) {
        int t = i - 65920;
        int h = t / 3136;                    // 49*64
        int r = t - h * 3136;
        int q = r >> 6;
        int key = r & 63;
        float v = (key < 49) ? bias_table[(size_t)rel_index[q * 49 + key] * 4 + h]
                             : -1e4f;
        ws[WS_BIAS + t] = (_Float16)v;
    }
}

// 512 threads = 8 waves: wave = (head h = w>>1, col-half c = w&1).
// No persistent weight registers: B-frags streamed from L2-resident f16 pack in
// d_ws inside rolled loops, so arch-VGPR demand fits the 64-reg budget the
// allocator pins for 512-thread kernels (rounds 3-6: metadata never moved it).
__global__ __launch_bounds__(512)
void lwa_fused(const float* __restrict__ x, const _Float16* __restrict__ ws,
               const float* __restrict__ b_proj, float* __restrict__ out,
               int nwin_total, int wpb)
{
    __shared__ __align__(16) _Float16 smem[SMEM_H];
    __shared__ float sums[4 * 2 * 64];   // [head][c][64 q-slots]

    const int tid  = threadIdx.x;
    const int w    = tid >> 6;
    const int h    = w >> 1;
    const int c    = w & 1;
    const int lane = tid & 63;
    const int lo   = lane & 15;
    const int hi   = lane >> 4;
    const int ncol = 32 * h + 16 * c + lo;

    _Float16* const Qh  = smem + PRIV0_H + h * PRIV_H;
    _Float16* const Kh  = Qh + K_OFF_H;
    _Float16* const Ph  = Qh;              // overlay: 49 x 64, stride 72
    _Float16* const VTh = Qh + VT_OFF_H;   // 32 x 64(+pad), stride 72

    const float bp = b_proj[ncol];
    const f32x4 zf = {0.f, 0.f, 0.f, 0.f};

    int b0 = blockIdx.x * wpb;
    int b1 = b0 + wpb; if (b1 > nwin_total) b1 = nwin_total;

    auto stage = [&](int bw, _Float16* dst) {
        const float* xs = x + (size_t)bw * NWIN * CDIM;
        int r0 = tid >> 4;
        int gc = (tid & 15) * 8;
#pragma unroll
        for (int p = 0; p < 2; ++p) {
            int row = r0 + p * 32;
            if (row < 49) {
                const float* sp = xs + (size_t)row * CDIM + gc;
                float4 u0 = *reinterpret_cast<const float4*>(sp);
                float4 u1 = *reinterpret_cast<const float4*>(sp + 4);
                half8 hh;
                hh[0] = (_Float16)u0.x; hh[1] = (_Float16)u0.y;
                hh[2] = (_Float16)u0.z; hh[3] = (_Float16)u0.w;
                hh[4] = (_Float16)u1.x; hh[5] = (_Float16)u1.y;
                hh[6] = (_Float16)u1.z; hh[7] = (_Float16)u1.w;
                *reinterpret_cast<half8*>(&dst[row * XL_STR + gc]) = hh;
            }
        }
    };

    stage(b0, smem);
    __syncthreads();

    for (int b = b0; b < b1; ++b) {
        const int par = (b - b0) & 1;
        _Float16* const xb = smem + (par ? XBUF_H : 0);
        _Float16* const xn = smem + (par ? 0 : XBUF_H);

        if (b + 1 < b1) stage(b + 1, xn);

        // ---- GEMM1: rolled tn (q,k,v) x rolled tm; B-frags streamed from ws ----
#pragma unroll 1
        for (int tn = 0; tn < 3; ++tn) {
            const _Float16* wbp = ws + WS_WQKV + ((size_t)(tn * CDIM + ncol)) * CDIM + hi * 8;
            half8 wf0 = *reinterpret_cast<const half8*>(wbp);
            half8 wf1 = *reinterpret_cast<const half8*>(wbp + 32);
            half8 wf2 = *reinterpret_cast<const half8*>(wbp + 64);
            half8 wf3 = *reinterpret_cast<const half8*>(wbp + 96);
            float bqv = (float)ws[WS_BQKV + tn * CDIM + ncol];
#pragma unroll 1
            for (int tm = 0; tm < 4; ++tm) {
                int ar = 16 * tm + lo; if (ar > 48) ar = 48;
                const _Float16* ap = &xb[ar * XL_STR + hi * 8];
                half8 a0 = *reinterpret_cast<const half8*>(ap);
                half8 a1 = *reinterpret_cast<const half8*>(ap + 32);
                half8 a2 = *reinterpret_cast<const half8*>(ap + 64);
                half8 a3 = *reinterpret_cast<const half8*>(ap + 96);
                f32x4 acc; acc[0] = bqv; acc[1] = bqv; acc[2] = bqv; acc[3] = bqv;
                acc = __builtin_amdgcn_mfma_f32_16x16x32_f16(a0, wf0, acc, 0, 0, 0);
                acc = __builtin_amdgcn_mfma_f32_16x16x32_f16(a1, wf1, acc, 0, 0, 0);
                acc = __builtin_amdgcn_mfma_f32_16x16x32_f16(a2, wf2, acc, 0, 0, 0);
                acc = __builtin_amdgcn_mfma_f32_16x16x32_f16(a3, wf3, acc, 0, 0, 0);
                if (tn == 2) {
                    half4v hv;
#pragma unroll
                    for (int j = 0; j < 4; ++j) hv[j] = (_Float16)acc[j];
                    *reinterpret_cast<half4v*>(&VTh[(16 * c + lo) * VT_STR + 16 * tm + 4 * hi]) = hv;
                } else {
                    _Float16* dst = (tn == 0) ? Qh : Kh;
#pragma unroll
                    for (int j = 0; j < 4; ++j) {
                        int row = 16 * tm + 4 * hi + j;
                        if (row < 49) dst[row * QK_STR + 16 * c + lo] = (_Float16)acc[j];
                    }
                }
            }
        }
        __syncthreads();  // B1: Q,K,VT visible; xb reads done

        // ---- hoist K,Q fragment reads (P overlays Q|K) ----
        half8 kf[2], qf[4];
#pragma unroll
        for (int kt = 0; kt < 2; ++kt) {
            int kr = 16 * (2 * c + kt) + lo; if (kr > 48) kr = 48;
            kf[kt] = *reinterpret_cast<const half8*>(&Kh[kr * QK_STR + hi * 8]);
        }
#pragma unroll
        for (int t = 0; t < 4; ++t)
            qf[t] = *reinterpret_cast<const half8*>(&Qh[(16 * t + lo) * QK_STR + hi * 8]);
        __syncthreads();  // B2: Q/K reads done -> P region writable

        // ---- S^T slice, exp, P stores, partial sums; bias streamed from ws ----
#pragma unroll
        for (int tnq = 0; tnq < 4; ++tnq) {
            int q = 16 * tnq + lo;
            int qc = (q < 49) ? q : 48;
            const _Float16* bb = ws + WS_BIAS + ((size_t)h * 49 + qc) * 64 + 32 * c + 4 * hi;
            float sum = 0.f;
#pragma unroll
            for (int kt = 0; kt < 2; ++kt) {
                f32x4 s = __builtin_amdgcn_mfma_f32_16x16x32_f16(kf[kt], qf[tnq], zf, 0, 0, 0);
                half4v bt = *reinterpret_cast<const half4v*>(bb + kt * 16);
                half4v hv;
#pragma unroll
                for (int j = 0; j < 4; ++j) {
                    float pv = __expf(s[j] + (float)bt[j]);
                    sum += pv;
                    hv[j] = (_Float16)pv;
                }
                if (q < 49)
                    *reinterpret_cast<half4v*>(&Ph[q * P_STR + 16 * (2 * c + kt) + 4 * hi]) = hv;
            }
            sum += __shfl_xor(sum, 16);
            sum += __shfl_xor(sum, 32);
            if (hi == 0) sums[h * 128 + c * 64 + q] = sum;
        }
        __syncthreads();  // B3: P + partial sums visible

        // ---- PV: O^T slice, normalized O -> xb ----
        {
            half8 vf0 = *reinterpret_cast<const half8*>(&VTh[(16 * c + lo) * VT_STR + hi * 8]);
            half8 vf1 = *reinterpret_cast<const half8*>(&VTh[(16 * c + lo) * VT_STR + 32 + hi * 8]);
#pragma unroll
            for (int tnq = 0; tnq < 4; ++tnq) {
                int q = 16 * tnq + lo;
                f32x4 o = zf;
                half8 pf0 = *reinterpret_cast<const half8*>(&Ph[q * P_STR + hi * 8]);
                half8 pf1 = *reinterpret_cast<const half8*>(&Ph[q * P_STR + 32 + hi * 8]);
                o = __builtin_amdgcn_mfma_f32_16x16x32_f16(vf0, pf0, o, 0, 0, 0);
                o = __builtin_amdgcn_mfma_f32_16x16x32_f16(vf1, pf1, o, 0, 0, 0);
                if (q < 49) {
                    float invl = 1.0f / (sums[h * 128 + q] + sums[h * 128 + 64 + q]);
                    half4v hv;
#pragma unroll
                    for (int j = 0; j < 4; ++j) hv[j] = (_Float16)(o[j] * invl);
                    *reinterpret_cast<half4v*>(&xb[q * XL_STR + 32 * h + 16 * c + 4 * hi]) = hv;
                }
            }
        }
        __syncthreads();  // B4: O complete

        // ---- GEMM3: rolled tm; w_proj frags streamed from ws ----
        {
            const _Float16* wpp = ws + WS_WPROJ + (size_t)ncol * CDIM + hi * 8;
            half8 p0 = *reinterpret_cast<const half8*>(wpp);
            half8 p1 = *reinterpret_cast<const half8*>(wpp + 32);
            half8 p2 = *reinterpret_cast<const half8*>(wpp + 64);
            half8 p3 = *reinterpret_cast<const half8*>(wpp + 96);
#pragma unroll 1
            for (int tm = 0; tm < 4; ++tm) {
                int orr = 16 * tm + lo; if (orr > 48) orr = 48;
                const _Float16* op = &xb[orr * XL_STR + hi * 8];
                half8 oa0 = *reinterpret_cast<const half8*>(op);
                half8 oa1 = *reinterpret_cast<const half8*>(op + 32);
                half8 oa2 = *reinterpret_cast<const half8*>(op + 64);
                half8 oa3 = *reinterpret_cast<const half8*>(op + 96);
                f32x4 g; g[0] = bp; g[1] = bp; g[2] = bp; g[3] = bp;
                g = __builtin_amdgcn_mfma_f32_16x16x32_f16(oa0, p0, g, 0, 0, 0);
                g = __builtin_amdgcn_mfma_f32_16x16x32_f16(oa1, p1, g, 0, 0, 0);
                g = __builtin_amdgcn_mfma_f32_16x16x32_f16(oa2, p2, g, 0, 0, 0);
                g = __builtin_amdgcn_mfma_f32_16x16x32_f16(oa3, p3, g, 0, 0, 0);
#pragma unroll
                for (int j = 0; j < 4; ++j) {
                    int row = 16 * tm + 4 * hi + j;
                    if (row < 49)
                        out[((size_t)b * NWIN + row) * CDIM + ncol] = g[j];
                }
            }
        }
        __syncthreads();  // B5: xb (O) reads done -> next iter may restage
    }
}

extern "C" void kernel_launch(void* const* d_in, const int* in_sizes, int n_in,
                              void* d_out, int out_size, void* d_ws, size_t ws_size,
                              hipStream_t stream) {
    const float* x          = (const float*)d_in[0];
    // d_in[1] = q_global: unused by the reference
    const float* w_qkv      = (const float*)d_in[2];
    const float* b_qkv      = (const float*)d_in[3];
    const float* w_proj     = (const float*)d_in[4];
    const float* b_proj     = (const float*)d_in[5];
    const float* bias_table = (const float*)d_in[6];
    const int*   rel_index  = (const int*)d_in[7];

    _Float16* ws = (_Float16*)d_ws;

    prepack<<<(WS_TOTAL + 255) / 256, 256, 0, stream>>>(w_qkv, b_qkv, w_proj,
                                                        bias_table, rel_index, ws);

    const int nwin = in_sizes[0] / (NWIN * CDIM);   // 16384
    const int wpb = 16;
    const int nblk = (nwin + wpb - 1) / wpb;        // 1024

    lwa_fused<<<nblk, 512, 0, stream>>>(x, ws, b_proj, (float*)d_out,
                                        nwin, wpb);
}